// Round 7
// baseline (6362.861 us; speedup 1.0000x reference)
//
#include <hip/hip_runtime.h>
#include <cstdint>

#define DEVFN static __device__ __forceinline__
typedef unsigned short ushort_t;
typedef unsigned int uint_t;
typedef short short8 __attribute__((ext_vector_type(8)));
typedef float f32x4 __attribute__((ext_vector_type(4)));

DEVFN float bf2f(ushort_t h) { return __uint_as_float(((uint_t)h) << 16); }
DEVFN ushort_t bfhi(float f) {
    uint_t u = __float_as_uint(f);
    u += 0x7fffu + ((u >> 16) & 1u);
    return (ushort_t)(u >> 16);
}
DEVFN void fsplit(float f, ushort_t& h, ushort_t& l) {
    h = bfhi(f);
    l = bfhi(f - bf2f(h));
}
// relu on a packed pair of bf16 hi/lo dwords (2 elements each)
DEVFN void relu_pair(uint_t& h, uint_t& l) {
    float f0 = bf2f((ushort_t)(h & 0xffffu)) + bf2f((ushort_t)(l & 0xffffu));
    float f1 = bf2f((ushort_t)(h >> 16)) + bf2f((ushort_t)(l >> 16));
    if (f0 <= 0.f) { h &= 0xffff0000u; l &= 0xffff0000u; }
    if (f1 <= 0.f) { h &= 0x0000ffffu; l &= 0x0000ffffu; }
}

// ============================================================================
// weight prep: fp32 [co][ci][k] -> bf16 hi/lo [tap][co][ci]
// ============================================================================
__global__ __launch_bounds__(256)
void wprep3_k(const float* __restrict__ erw, const float* __restrict__ drw,
              ushort_t* __restrict__ wH, ushort_t* __restrict__ wL)
{
    const int gid = blockIdx.x * 256 + threadIdx.x;   // 80*65536 threads
    const int conv = gid >> 16;
    const int rem  = gid & 65535;                      // co*256+ci
    const int co = rem >> 8, ci = rem & 255;
    const float* src = (conv < 40) ? (erw + (size_t)conv * 196608)
                                   : (drw + (size_t)(conv - 40) * 196608);
    const float* p = src + ((size_t)co * 256 + ci) * 3;
    ushort_t* oh = wH + (size_t)conv * 196608 + rem;
    ushort_t* ol = wL + (size_t)conv * 196608 + rem;
#pragma unroll
    for (int k = 0; k < 3; ++k) {
        ushort_t h, l; fsplit(p[k], h, l);
        oh[k * 65536] = h; ol[k * 65536] = l;
    }
}

__global__ __launch_bounds__(256)
void wprep4_k(const float* __restrict__ edw, const float* __restrict__ duw,
              ushort_t* __restrict__ wH, ushort_t* __restrict__ wL)
{
    const int gid = blockIdx.x * 256 + threadIdx.x;   // 8*65536 threads
    const int conv = gid >> 16;
    const int rem  = gid & 65535;
    const int co = rem >> 8, ci = rem & 255;
    ushort_t* oh = wH + (size_t)conv * 262144 + rem;
    ushort_t* ol = wL + (size_t)conv * 262144 + rem;
#pragma unroll
    for (int k = 0; k < 4; ++k) {
        float f;
        if (conv < 4)  f = edw[(size_t)conv * 262144 + ((size_t)co * 256 + ci) * 4 + k];
        else           f = duw[(size_t)(conv - 4) * 262144 + ((size_t)ci * 256 + co) * 4 + k];
        ushort_t h, l; fsplit(f, h, l);
        oh[k * 65536] = h; ol[k * 65536] = l;
    }
}

// ============================================================================
// conv3 (dilated, relu'd input, out = alpha*src + conv + bias), split MFMA.
// Block: 128 co x NTT*16 t ; 4 waves x 32 co. grid (L/ROWS, 2 co-halves, 2 b).
// Small tile + low VGPR -> 4 blocks/CU (16 waves) for latency hiding.
// ============================================================================
template<bool RELU, int NTT>
__global__ __launch_bounds__(256, 4)
void conv3n_k(const ushort_t* __restrict__ inH, const ushort_t* __restrict__ inL,
              const ushort_t* __restrict__ wH, const ushort_t* __restrict__ wL,
              const float* __restrict__ bias,
              const ushort_t* __restrict__ srcH, const ushort_t* __restrict__ srcL,
              float alpha,
              ushort_t* __restrict__ outH, ushort_t* __restrict__ outL,
              int L, int dil)
{
    constexpr int ROWS = NTT * 16;
    constexpr int SMAX = ROWS + 162;            // dil <= 81
    constexpr int XSB  = SMAX * 40 * 2;         // bytes per plane
    constexpr int EBUF = 16 * 132 * 4;
    constexpr int ARENA = (2 * XSB > EBUF) ? 2 * XSB : EBUF;
    __shared__ __align__(16) char sarena[ARENA];
    ushort_t (*xsH)[40] = (ushort_t(*)[40])(sarena);
    ushort_t (*xsL)[40] = (ushort_t(*)[40])(sarena + XSB);

    const int tid = threadIdx.x;
    const int b = blockIdx.z;
    const int co0 = blockIdx.y * 128;
    const int t0 = blockIdx.x * ROWS;
    const int wave = tid >> 6, lane = tid & 63;
    const int quad = lane >> 4, lr = lane & 15;
    const int cow = co0 + wave * 32;            // wave covers 32 co (2 m of 16)
    const size_t inbase = (size_t)b * L * 256;
    const int S = ROWS + 2 * dil;
    const int g0 = t0 - dil;

    f32x4 acc[2][NTT];
#pragma unroll
    for (int m = 0; m < 2; ++m)
#pragma unroll
        for (int n = 0; n < NTT; ++n) acc[m][n] = (f32x4)0.f;

    for (int chunk = 0; chunk < 8; ++chunk) {
        const int ci0 = chunk * 32;
        __syncthreads();
        // ---- stage x halo: S rows x 32 ci (once, all taps) ----
        for (int idx = tid; idx < S * 4; idx += 256) {
            const int s = idx >> 2, p = idx & 3;
            const int t = g0 + s;
            uint4 hv = make_uint4(0, 0, 0, 0), lv = hv;
            if (t >= 0 && t < L) {
                const size_t g = inbase + (size_t)t * 256 + ci0 + p * 8;
                hv = *(const uint4*)(inH + g);
                lv = *(const uint4*)(inL + g);
                if (RELU) {
                    relu_pair(hv.x, lv.x); relu_pair(hv.y, lv.y);
                    relu_pair(hv.z, lv.z); relu_pair(hv.w, lv.w);
                }
            }
            *(uint4*)&xsH[s][p * 8] = hv;
            *(uint4*)&xsL[s][p * 8] = lv;
        }
        __syncthreads();
        // ---- compute: taps inner, A (weights) straight from global/L2 ----
#pragma unroll
        for (int tap = 0; tap < 3; ++tap) {
            const ushort_t* wHt = wH + (size_t)tap * 65536 + ci0 + quad * 8;
            const ushort_t* wLt = wL + (size_t)tap * 65536 + ci0 + quad * 8;
            short8 aH[2], aL[2];
#pragma unroll
            for (int m = 0; m < 2; ++m) {
                const int co = cow + m * 16 + lr;
                aH[m] = *(const short8*)(wHt + co * 256);
                aL[m] = *(const short8*)(wLt + co * 256);
            }
            const int rb = tap * dil;
#pragma unroll
            for (int n = 0; n < NTT; ++n) {
                const int srow = n * 16 + lr + rb;
                const short8 bH = *(const short8*)&xsH[srow][quad * 8];
                const short8 bL = *(const short8*)&xsL[srow][quad * 8];
#pragma unroll
                for (int m = 0; m < 2; ++m)
                    acc[m][n] = __builtin_amdgcn_mfma_f32_16x16x32_bf16(aH[m], bH, acc[m][n], 0, 0, 0);
#pragma unroll
                for (int m = 0; m < 2; ++m)
                    acc[m][n] = __builtin_amdgcn_mfma_f32_16x16x32_bf16(aH[m], bL, acc[m][n], 0, 0, 0);
#pragma unroll
                for (int m = 0; m < 2; ++m)
                    acc[m][n] = __builtin_amdgcn_mfma_f32_16x16x32_bf16(aL[m], bH, acc[m][n], 0, 0, 0);
            }
        }
    }
    // ---- coalesced epilogue: 16 t-rows x 128 co through LDS ----
    float4 bvv[2];
#pragma unroll
    for (int m = 0; m < 2; ++m)
        bvv[m] = *(const float4*)&bias[cow + m * 16 + quad * 4];
    __syncthreads();
    float (*ebuf)[132] = (float(*)[132])sarena;
#pragma unroll
    for (int n = 0; n < NTT; ++n) {
#pragma unroll
        for (int m = 0; m < 2; ++m) {
            float4 v;
            v.x = acc[m][n][0] + bvv[m].x;
            v.y = acc[m][n][1] + bvv[m].y;
            v.z = acc[m][n][2] + bvv[m].z;
            v.w = acc[m][n][3] + bvv[m].w;
            *(float4*)&ebuf[lr][wave * 32 + m * 16 + quad * 4] = v;
        }
        __syncthreads();
        {
            const int row = tid >> 4;
            const int c00 = (tid & 15) * 4;
            const int t = t0 + n * 16 + row;
            const size_t gr = ((size_t)b * L + t) * 256 + co0;
#pragma unroll
            for (int rep = 0; rep < 2; ++rep) {
                const int col = c00 + rep * 64;
                float4 v = *(const float4*)&ebuf[row][col];
                if (alpha != 0.f) {
                    const ushort4 sh = *(const ushort4*)(srcH + gr + col);
                    const ushort4 sl = *(const ushort4*)(srcL + gr + col);
                    v.x += alpha * (bf2f(sh.x) + bf2f(sl.x));
                    v.y += alpha * (bf2f(sh.y) + bf2f(sl.y));
                    v.z += alpha * (bf2f(sh.z) + bf2f(sl.z));
                    v.w += alpha * (bf2f(sh.w) + bf2f(sl.w));
                }
                ushort4 oh, ol;
                fsplit(v.x, oh.x, ol.x); fsplit(v.y, oh.y, ol.y);
                fsplit(v.z, oh.z, ol.z); fsplit(v.w, oh.w, ol.w);
                *(ushort4*)(outH + gr + col) = oh;
                *(ushort4*)(outL + gr + col) = ol;
            }
        }
        __syncthreads();
    }
}

// ============================================================================
// strided conv k=4 s=2 (downsample), 256co x NT*16 t blocks, x halo staged once
// ============================================================================
template<int NT>
__global__ __launch_bounds__(256, (NT >= 8) ? 2 : 3)
void convs_k(const ushort_t* __restrict__ inH, const ushort_t* __restrict__ inL,
             const ushort_t* __restrict__ wH, const ushort_t* __restrict__ wL,
             const float* __restrict__ bias,
             ushort_t* __restrict__ outH, ushort_t* __restrict__ outL,
             int Lin, int Lout)
{
    constexpr int ROWS = NT * 16;
    constexpr int SMAX = 2 * (ROWS - 1) + 4;
    constexpr int XSB  = SMAX * 40 * 2;
    constexpr int ARENA = (2 * XSB > 16640) ? 2 * XSB : 16640;
    __shared__ __align__(16) char sarena[ARENA];
    ushort_t (*xsH)[40] = (ushort_t(*)[40])(sarena);
    ushort_t (*xsL)[40] = (ushort_t(*)[40])(sarena + XSB);

    const int tid = threadIdx.x;
    const int b = blockIdx.z;
    const int t0 = blockIdx.x * ROWS;
    const int wave = tid >> 6, lane = tid & 63;
    const int quad = lane >> 4, lr = lane & 15;
    const int cow = wave * 64;
    const size_t inbase = (size_t)b * Lin * 256;
    const int S = 2 * (ROWS - 1) + 4;
    const int g0 = 2 * t0 - 1;

    f32x4 acc[4][NT];
#pragma unroll
    for (int m = 0; m < 4; ++m)
#pragma unroll
        for (int n = 0; n < NT; ++n) acc[m][n] = (f32x4)0.f;

    for (int chunk = 0; chunk < 8; ++chunk) {
        const int ci0 = chunk * 32;
        __syncthreads();
        for (int idx = tid; idx < S * 4; idx += 256) {
            const int s = idx >> 2, p = idx & 3;
            const int t = g0 + s;
            uint4 hv = make_uint4(0, 0, 0, 0), lv = hv;
            if (t >= 0 && t < Lin) {
                const size_t g = inbase + (size_t)t * 256 + ci0 + p * 8;
                hv = *(const uint4*)(inH + g);
                lv = *(const uint4*)(inL + g);
            }
            *(uint4*)&xsH[s][p * 8] = hv;
            *(uint4*)&xsL[s][p * 8] = lv;
        }
        __syncthreads();
#pragma unroll
        for (int tap = 0; tap < 4; ++tap) {
            const ushort_t* wHt = wH + (size_t)tap * 65536 + ci0 + quad * 8;
            const ushort_t* wLt = wL + (size_t)tap * 65536 + ci0 + quad * 8;
            short8 aH[4], aL[4];
#pragma unroll
            for (int m = 0; m < 4; ++m) {
                const int co = cow + m * 16 + lr;
                aH[m] = *(const short8*)(wHt + co * 256);
                aL[m] = *(const short8*)(wLt + co * 256);
            }
#pragma unroll
            for (int n = 0; n < NT; ++n) {
                const int srow = 2 * (n * 16 + lr) + tap;
                const short8 bH = *(const short8*)&xsH[srow][quad * 8];
                const short8 bL = *(const short8*)&xsL[srow][quad * 8];
#pragma unroll
                for (int m = 0; m < 4; ++m)
                    acc[m][n] = __builtin_amdgcn_mfma_f32_16x16x32_bf16(aH[m], bH, acc[m][n], 0, 0, 0);
#pragma unroll
                for (int m = 0; m < 4; ++m)
                    acc[m][n] = __builtin_amdgcn_mfma_f32_16x16x32_bf16(aH[m], bL, acc[m][n], 0, 0, 0);
#pragma unroll
                for (int m = 0; m < 4; ++m)
                    acc[m][n] = __builtin_amdgcn_mfma_f32_16x16x32_bf16(aL[m], bH, acc[m][n], 0, 0, 0);
            }
        }
    }
    float4 bvv[4];
#pragma unroll
    for (int m = 0; m < 4; ++m)
        bvv[m] = *(const float4*)&bias[cow + m * 16 + quad * 4];
    __syncthreads();
    float (*ebuf)[260] = (float(*)[260])sarena;
#pragma unroll
    for (int n = 0; n < NT; ++n) {
#pragma unroll
        for (int m = 0; m < 4; ++m) {
            float4 v;
            v.x = acc[m][n][0] + bvv[m].x;
            v.y = acc[m][n][1] + bvv[m].y;
            v.z = acc[m][n][2] + bvv[m].z;
            v.w = acc[m][n][3] + bvv[m].w;
            *(float4*)&ebuf[lr][cow + m * 16 + quad * 4] = v;
        }
        __syncthreads();
        {
            const int row = tid >> 4;
            const int c00 = (tid & 15) * 4;
            const int t = t0 + n * 16 + row;
            const size_t gr = ((size_t)b * Lout + t) * 256;
#pragma unroll
            for (int rep = 0; rep < 4; ++rep) {
                const int col = c00 + rep * 64;
                float4 v = *(const float4*)&ebuf[row][col];
                ushort4 oh, ol;
                fsplit(v.x, oh.x, ol.x); fsplit(v.y, oh.y, ol.y);
                fsplit(v.z, oh.z, ol.z); fsplit(v.w, oh.w, ol.w);
                *(ushort4*)(outH + gr + col) = oh;
                *(ushort4*)(outL + gr + col) = ol;
            }
        }
        __syncthreads();
    }
}

// ============================================================================
// conv transpose k=4 s=2 p=1 (split MFMA). Block: NTc*16 input m x 256 co.
// taps fully unrolled (runtime-indexed acc goes to scratch — R4 lesson).
// ============================================================================
template<int NTc>
__global__ __launch_bounds__(256, 2)
void convt_k(const ushort_t* __restrict__ inH, const ushort_t* __restrict__ inL,
             const ushort_t* __restrict__ wH, const ushort_t* __restrict__ wL,
             const float* __restrict__ bias,
             ushort_t* __restrict__ outH, ushort_t* __restrict__ outL, int Lin)
{
    constexpr int ROWS = NTc * 16;
    constexpr int S = ROWS + 2;
    constexpr int XSB = S * 40 * 2;
    constexpr int ARENA = (2 * XSB > 33280) ? 2 * XSB : 33280;
    __shared__ __align__(16) char sarena[ARENA];
    ushort_t (*xsH)[40] = (ushort_t(*)[40])(sarena);
    ushort_t (*xsL)[40] = (ushort_t(*)[40])(sarena + XSB);

    const int tid = threadIdx.x;
    const int b = blockIdx.z;
    const int m0 = blockIdx.x * ROWS;
    const int Lout = Lin * 2;
    const int wave = tid >> 6, lane = tid & 63;
    const int quad = lane >> 4, lr = lane & 15;
    const int cow = wave * 64;
    const size_t inbase = (size_t)b * Lin * 256;

    f32x4 acc[4][NTc][2];
#pragma unroll
    for (int m = 0; m < 4; ++m)
#pragma unroll
        for (int n = 0; n < NTc; ++n) { acc[m][n][0] = (f32x4)0.f; acc[m][n][1] = (f32x4)0.f; }

    for (int chunk = 0; chunk < 8; ++chunk) {
        const int ci0 = chunk * 32;
        __syncthreads();
        for (int idx = tid; idx < S * 4; idx += 256) {
            const int s = idx >> 2, p = idx & 3;
            const int t = m0 - 1 + s;
            uint4 hv = make_uint4(0, 0, 0, 0), lv = hv;
            if (t >= 0 && t < Lin) {
                const size_t g = inbase + (size_t)t * 256 + ci0 + p * 8;
                hv = *(const uint4*)(inH + g);
                lv = *(const uint4*)(inL + g);
            }
            *(uint4*)&xsH[s][p * 8] = hv;
            *(uint4*)&xsL[s][p * 8] = lv;
        }
        __syncthreads();
#pragma unroll
        for (int tap = 0; tap < 4; ++tap) {
            const int ph = (tap == 0 || tap == 2) ? 1 : 0;
            const int sh = (tap == 0) ? 1 : ((tap == 3) ? -1 : 0);
            const ushort_t* wHt = wH + (size_t)tap * 65536 + ci0 + quad * 8;
            const ushort_t* wLt = wL + (size_t)tap * 65536 + ci0 + quad * 8;
            short8 aH[4], aL[4];
#pragma unroll
            for (int m = 0; m < 4; ++m) {
                const int co = cow + m * 16 + lr;
                aH[m] = *(const short8*)(wHt + co * 256);
                aL[m] = *(const short8*)(wLt + co * 256);
            }
#pragma unroll
            for (int n = 0; n < NTc; ++n) {
                const int srow = n * 16 + lr + sh + 1;
                const short8 bH = *(const short8*)&xsH[srow][quad * 8];
                const short8 bL = *(const short8*)&xsL[srow][quad * 8];
#pragma unroll
                for (int m = 0; m < 4; ++m)
                    acc[m][n][ph] = __builtin_amdgcn_mfma_f32_16x16x32_bf16(aH[m], bH, acc[m][n][ph], 0, 0, 0);
#pragma unroll
                for (int m = 0; m < 4; ++m)
                    acc[m][n][ph] = __builtin_amdgcn_mfma_f32_16x16x32_bf16(aH[m], bL, acc[m][n][ph], 0, 0, 0);
#pragma unroll
                for (int m = 0; m < 4; ++m)
                    acc[m][n][ph] = __builtin_amdgcn_mfma_f32_16x16x32_bf16(aL[m], bH, acc[m][n][ph], 0, 0, 0);
            }
        }
    }
    float4 bvv[4];
#pragma unroll
    for (int m = 0; m < 4; ++m)
        bvv[m] = *(const float4*)&bias[cow + m * 16 + quad * 4];
    __syncthreads();
    float (*ebuf)[260] = (float(*)[260])sarena;
#pragma unroll
    for (int n = 0; n < NTc; ++n) {
#pragma unroll
        for (int m = 0; m < 4; ++m) {
#pragma unroll
            for (int ph = 0; ph < 2; ++ph) {
                float4 v;
                v.x = acc[m][n][ph][0] + bvv[m].x;
                v.y = acc[m][n][ph][1] + bvv[m].y;
                v.z = acc[m][n][ph][2] + bvv[m].z;
                v.w = acc[m][n][ph][3] + bvv[m].w;
                *(float4*)&ebuf[2 * lr + ph][cow + m * 16 + quad * 4] = v;
            }
        }
        __syncthreads();
        {
            const int baset = 2 * (m0 + n * 16);
#pragma unroll
            for (int h = 0; h < 8; ++h) {
                const int row = (tid >> 4) + 16 * (h >> 2);
                const int col = (tid & 15) * 4 + (h & 3) * 64;
                const int t = baset + row;
                const size_t gr = ((size_t)b * Lout + t) * 256 + col;
                float4 v = *(const float4*)&ebuf[row][col];
                ushort4 oh, ol;
                fsplit(v.x, oh.x, ol.x); fsplit(v.y, oh.y, ol.y);
                fsplit(v.z, oh.z, ol.z); fsplit(v.w, oh.w, ol.w);
                *(ushort4*)(outH + gr) = oh;
                *(ushort4*)(outL + gr) = ol;
            }
        }
        __syncthreads();
    }
}

// ============================================================================
// first conv 1->256 k=4 s=2 p=1 ; writes [b][t][c] hi/lo
// ============================================================================
__global__ __launch_bounds__(256)
void down0_k2(const float* __restrict__ x, const float* __restrict__ w,
              const float* __restrict__ bias,
              ushort_t* __restrict__ outH, ushort_t* __restrict__ outL)
{
    const int t = blockIdx.x;               // 32768
    const int b = blockIdx.y;
    const int co = threadIdx.x;
    const float* xb = x + (size_t)b * 65536;
    const float4 wv = *(const float4*)(w + co * 4);
    float s = bias[co];
    const int ti0 = 2 * t - 1;
    if (ti0 >= 0)      s = fmaf(xb[ti0], wv.x, s);
    s = fmaf(xb[ti0 + 1], wv.y, s);
    s = fmaf(xb[ti0 + 2], wv.z, s);
    if (ti0 + 3 < 65536) s = fmaf(xb[ti0 + 3], wv.w, s);
    ushort_t h, l; fsplit(s, h, l);
    const size_t g = ((size_t)b * 32768 + t) * 256 + co;
    outH[g] = h; outL[g] = l;
}

// ============================================================================
// last conv transpose 256->1
// ============================================================================
__global__ __launch_bounds__(256)
void uplast_k2(const ushort_t* __restrict__ inH, const ushort_t* __restrict__ inL,
               const float* __restrict__ w, const float* __restrict__ bias,
               float* __restrict__ out, int Lin)
{
    const int m = blockIdx.x * 256 + threadIdx.x;
    const int b = blockIdx.y;
    const float bv = bias[0];
    float aE = bv, aO = bv;
    const size_t base = (size_t)b * Lin * 256;
    const ushort_t* r0H = inH + base + (size_t)m * 256;
    const ushort_t* r0L = inL + base + (size_t)m * 256;
    const bool hasM = (m > 0), hasP = (m + 1 < Lin);
    for (int c0 = 0; c0 < 256; c0 += 8) {
        uint4 h0 = *(const uint4*)(r0H + c0);
        uint4 l0 = *(const uint4*)(r0L + c0);
        uint4 hm = make_uint4(0,0,0,0), lm = hm, hp = hm, lp = hm;
        if (hasM) { hm = *(const uint4*)(r0H - 256 + c0); lm = *(const uint4*)(r0L - 256 + c0); }
        if (hasP) { hp = *(const uint4*)(r0H + 256 + c0); lp = *(const uint4*)(r0L + 256 + c0); }
        const uint_t* h0p = (const uint_t*)&h0; const uint_t* l0p = (const uint_t*)&l0;
        const uint_t* hmp = (const uint_t*)&hm; const uint_t* lmp = (const uint_t*)&lm;
        const uint_t* hpp = (const uint_t*)&hp; const uint_t* lpp = (const uint_t*)&lp;
#pragma unroll
        for (int e = 0; e < 4; ++e) {
#pragma unroll
            for (int half = 0; half < 2; ++half) {
                const int sh = half * 16;
                const int ci = c0 + e * 2 + half;
                const float x0  = bf2f((ushort_t)(h0p[e] >> sh)) + bf2f((ushort_t)(l0p[e] >> sh));
                const float xm1 = bf2f((ushort_t)(hmp[e] >> sh)) + bf2f((ushort_t)(lmp[e] >> sh));
                const float xp1 = bf2f((ushort_t)(hpp[e] >> sh)) + bf2f((ushort_t)(lpp[e] >> sh));
                const float4 wv = *(const float4*)(w + ci * 4);
                aE = fmaf(x0, wv.y, fmaf(xm1, wv.w, aE));
                aO = fmaf(xp1, wv.x, fmaf(x0, wv.z, aO));
            }
        }
    }
    *(float2*)(out + (size_t)b * 2 * Lin + 2 * m) = make_float2(aE, aO);
}

// ============================================================================
// act <-> fp32 emb/q
// ============================================================================
__global__ void emb_k(const ushort_t* __restrict__ H, const ushort_t* __restrict__ L,
                      float* __restrict__ emb)
{
    const size_t g = (size_t)blockIdx.x * 256 + threadIdx.x;
    emb[g] = bf2f(H[g]) + bf2f(L[g]);
}
__global__ void qsplit_k(const float* __restrict__ q,
                         ushort_t* __restrict__ H, ushort_t* __restrict__ L)
{
    const size_t g = (size_t)blockIdx.x * 256 + threadIdx.x;
    ushort_t h, l; fsplit(q[g], h, l);
    H[g] = h; L[g] = l;
}

// ============================================================================
// RVQ (fp32)
// ============================================================================
__global__ __launch_bounds__(256)
void rvq_cb_k(const float* __restrict__ sum, const float* __restrict__ usage,
              float* __restrict__ cb, float* __restrict__ cbT,
              float* __restrict__ cbn, int iq)
{
    const int k = blockIdx.x, c = threadIdx.x;
    const float den = fmaxf(usage[iq * 1024 + k], 1e-5f);
    const float v = sum[((size_t)iq * 1024 + k) * 256 + c] / den;
    cb[(size_t)k * 256 + c] = v;
    cbT[(size_t)c * 1024 + k] = v;
    float s = v * v;
    for (int off = 32; off; off >>= 1) s += __shfl_down(s, off, 64);
    __shared__ float ls[4];
    if ((c & 63) == 0) ls[c >> 6] = s;
    __syncthreads();
    if (c == 0) cbn[k] = ls[0] + ls[1] + ls[2] + ls[3];
}

DEVFN unsigned int ordbits(float f)
{
    unsigned u = __float_as_uint(f);
    return (u & 0x80000000u) ? ~u : (u | 0x80000000u);
}
DEVFN unsigned long long shfl_xor_u64(unsigned long long v, int mask)
{
    int lo = (int)(v & 0xffffffffull), hi = (int)(v >> 32);
    lo = __shfl_xor(lo, mask, 64);
    hi = __shfl_xor(hi, mask, 64);
    return ((unsigned long long)(unsigned)hi << 32) | (unsigned)lo;
}

__global__ __launch_bounds__(256)
void rvq_argmin_k(const float* __restrict__ emb, const float* __restrict__ q,
                  const float* __restrict__ cbT, const float* __restrict__ cbn,
                  int* __restrict__ codes, float* __restrict__ codes_out, int iq)
{
    const int n0 = blockIdx.x * 16;
    const int tid = threadIdx.x;
    __shared__ float res[16][256];
    for (int idx = tid; idx < 16 * 256; idx += 256) {
        int nl = idx >> 8, c = idx & 255;
        size_t g = (size_t)(n0 + nl) * 256 + c;
        res[nl][c] = emb[g] - q[g];
    }
    __syncthreads();
    float dot[16][4];
#pragma unroll
    for (int nl = 0; nl < 16; ++nl)
#pragma unroll
        for (int j = 0; j < 4; ++j) dot[nl][j] = 0.f;

    const float* cbtp = cbT + tid * 4;
    for (int c = 0; c < 256; ++c) {
        const float4 cbv = *(const float4*)(cbtp + (size_t)c * 1024);
#pragma unroll
        for (int nl = 0; nl < 16; ++nl) {
            const float r = res[nl][c];
            dot[nl][0] = fmaf(cbv.x, r, dot[nl][0]);
            dot[nl][1] = fmaf(cbv.y, r, dot[nl][1]);
            dot[nl][2] = fmaf(cbv.z, r, dot[nl][2]);
            dot[nl][3] = fmaf(cbv.w, r, dot[nl][3]);
        }
    }
    const float4 nrm = *(const float4*)(cbn + tid * 4);
    __shared__ unsigned long long wred[4][16];
    const int wave = tid >> 6, lane = tid & 63;
#pragma unroll
    for (int nl = 0; nl < 16; ++nl) {
        float s0 = nrm.x - 2.f * dot[nl][0];
        float s1 = nrm.y - 2.f * dot[nl][1];
        float s2 = nrm.z - 2.f * dot[nl][2];
        float s3 = nrm.w - 2.f * dot[nl][3];
        unsigned long long key =
            ((unsigned long long)ordbits(s0) << 32) | (unsigned)(tid * 4 + 0);
        unsigned long long k1 =
            ((unsigned long long)ordbits(s1) << 32) | (unsigned)(tid * 4 + 1);
        unsigned long long k2 =
            ((unsigned long long)ordbits(s2) << 32) | (unsigned)(tid * 4 + 2);
        unsigned long long k3 =
            ((unsigned long long)ordbits(s3) << 32) | (unsigned)(tid * 4 + 3);
        if (k1 < key) key = k1;
        if (k2 < key) key = k2;
        if (k3 < key) key = k3;
        for (int off = 32; off; off >>= 1) {
            unsigned long long o = shfl_xor_u64(key, off);
            if (o < key) key = o;
        }
        if (lane == 0) wred[wave][nl] = key;
    }
    __syncthreads();
    if (tid < 16) {
        unsigned long long bkey = wred[0][tid];
        if (wred[1][tid] < bkey) bkey = wred[1][tid];
        if (wred[2][tid] < bkey) bkey = wred[2][tid];
        if (wred[3][tid] < bkey) bkey = wred[3][tid];
        const int code = (int)(bkey & 0xffffffffull);
        codes[(size_t)(n0 + tid) * 8 + iq] = code;
        codes_out[(size_t)(n0 + tid) * 8 + iq] = (float)code;
    }
}

__global__ __launch_bounds__(256)
void rvq_update_k(const float* __restrict__ emb, float* __restrict__ q,
                  const float* __restrict__ cb, const int* __restrict__ codes,
                  float* __restrict__ commit, int iq)
{
    const int n = blockIdx.x, c = threadIdx.x;
    const int code = codes[(size_t)n * 8 + iq];
    const size_t g = (size_t)n * 256 + c;
    const float qv = q[g] + cb[(size_t)code * 256 + c];
    q[g] = qv;
    const float e = qv - emb[g];
    float s = e * e;
    for (int off = 32; off; off >>= 1) s += __shfl_down(s, off, 64);
    __shared__ float ls[4];
    if ((c & 63) == 0) ls[c >> 6] = s;
    __syncthreads();
    if (c == 0) atomicAdd(commit, ls[0] + ls[1] + ls[2] + ls[3]);
}

__global__ void commit_write_k(const float* __restrict__ commit, float* __restrict__ out)
{
    out[0] = commit[0] * (1.f / (4096.f * 256.f));
}

// ============================================================================
extern "C" void kernel_launch(void* const* d_in, const int* in_sizes, int n_in,
                              void* d_out, int out_size, void* d_ws, size_t ws_size,
                              hipStream_t stream)
{
    const float* x    = (const float*)d_in[0];
    const float* ed0w = (const float*)d_in[1];
    const float* ed0b = (const float*)d_in[2];
    const float* edw  = (const float*)d_in[3];
    const float* edb  = (const float*)d_in[4];
    const float* erw  = (const float*)d_in[5];
    const float* erb  = (const float*)d_in[6];
    const float* drw  = (const float*)d_in[7];
    const float* drb  = (const float*)d_in[8];
    const float* duw  = (const float*)d_in[9];
    const float* dub  = (const float*)d_in[10];
    const float* dulw = (const float*)d_in[11];
    const float* dulb = (const float*)d_in[12];
    const float* rsum = (const float*)d_in[13];
    const float* rusg = (const float*)d_in[14];
    float* out = (float*)d_out;

    char* base = (char*)d_ws;
    size_t o = 0;
    ushort_t* wH3 = (ushort_t*)(base + o); o += 31457280;   // 80*3*65536 bf16
    ushort_t* wL3 = (ushort_t*)(base + o); o += 31457280;
    ushort_t* w4H = (ushort_t*)(base + o); o += 4194304;    // 8*4*65536 bf16
    ushort_t* w4L = (ushort_t*)(base + o); o += 4194304;
    ushort_t* AH  = (ushort_t*)(base + o); o += 33554432;   // act [2][32768][256]
    ushort_t* AL  = (ushort_t*)(base + o); o += 33554432;
    ushort_t* BH  = (ushort_t*)(base + o); o += 33554432;
    ushort_t* BL  = (ushort_t*)(base + o); o += 33554432;
    float* emb    = (float*)(base + o);    o += 4194304;
    float* q      = (float*)(base + o);    o += 4194304;
    float* commit = (float*)(base + o);    o += 64;
    float* cb     = (float*)(base + o);    o += 1048576;
    float* cbT    = (float*)(base + o);    o += 1048576;
    float* cbn    = (float*)(base + o);    o += 4096;
    int*   codes  = (int*)(base + o);      o += 131072;

    static const int DIL[4] = {3, 9, 27, 81};

    hipMemsetAsync(q, 0, 4194304 + 64, stream);   // q + commit

    // weight prep
    wprep3_k<<<20480, 256, 0, stream>>>(erw, drw, wH3, wL3);
    wprep4_k<<<2048, 256, 0, stream>>>(edw, duw, w4H, w4L);

    // conv3: 128co x 64t tiles (NTT=4) when L>=16384; NTT=2 below
    auto conv3 = [&](const ushort_t* iH, const ushort_t* iL,
                     const ushort_t* wh, const ushort_t* wl, const float* bb,
                     const ushort_t* sH, const ushort_t* sL, float alpha,
                     ushort_t* oH, ushort_t* oL, int L, int d) {
        if (L >= 16384)
            conv3n_k<true, 4><<<dim3(L / 64, 2, 2), 256, 0, stream>>>(
                iH, iL, wh, wl, bb, sH, sL, alpha, oH, oL, L, d);
        else
            conv3n_k<true, 2><<<dim3(L / 32, 2, 2), 256, 0, stream>>>(
                iH, iL, wh, wl, bb, sH, sL, alpha, oH, oL, L, d);
    };

    // -------------------- encoder --------------------
    down0_k2<<<dim3(32768, 2), 256, 0, stream>>>(x, ed0w, ed0b, AH, AL);
    int L = 32768;
    for (int i = 0; i < 5; ++i) {
        if (i > 0) {
            const ushort_t* wh = w4H + (size_t)(i - 1) * 262144;
            const ushort_t* wl = w4L + (size_t)(i - 1) * 262144;
            const int Lout = L / 2;
            if (Lout >= 16384)
                convs_k<8><<<dim3(Lout / 128, 1, 2), 256, 0, stream>>>(
                    AH, AL, wh, wl, edb + (i - 1) * 256, BH, BL, L, Lout);
            else if (Lout >= 4096)
                convs_k<4><<<dim3(Lout / 64, 1, 2), 256, 0, stream>>>(
                    AH, AL, wh, wl, edb + (i - 1) * 256, BH, BL, L, Lout);
            else
                convs_k<2><<<dim3(Lout / 32, 1, 2), 256, 0, stream>>>(
                    AH, AL, wh, wl, edb + (i - 1) * 256, BH, BL, L, Lout);
            ushort_t* t;
            t = AH; AH = BH; BH = t;
            t = AL; AL = BL; BL = t;
            L = Lout;
        }
        for (int j = 0; j < 4; ++j) {
            const int d = DIL[j];
            const size_t u = (size_t)(i * 4 + j) * 2;
            conv3(AH, AL, wH3 + (u + 0) * 196608, wL3 + (u + 0) * 196608,
                  erb + (u + 0) * 256, AH, AL, 0.f, BH, BL, L, d);
            conv3(BH, BL, wH3 + (u + 1) * 196608, wL3 + (u + 1) * 196608,
                  erb + (u + 1) * 256, AH, AL, 1.f, AH, AL, L, 1);
        }
    }

    // -------------------- RVQ --------------------
    emb_k<<<4096, 256, 0, stream>>>(AH, AL, emb);
    for (int iq = 0; iq < 8; ++iq) {
        rvq_cb_k<<<1024, 256, 0, stream>>>(rsum, rusg, cb, cbT, cbn, iq);
        rvq_argmin_k<<<256, 256, 0, stream>>>(emb, q, cbT, cbn, codes, out + 131072, iq);
        rvq_update_k<<<4096, 256, 0, stream>>>(emb, q, cb, codes, commit, iq);
    }
    qsplit_k<<<4096, 256, 0, stream>>>(q, AH, AL);

    // -------------------- decoder --------------------
    L = 2048;
    for (int i = 0; i < 5; ++i) {
        for (int j = 0; j < 4; ++j) {
            const int d = DIL[j];
            const size_t u = 40 + (size_t)(i * 4 + j) * 2;   // decoder slabs 40..79
            conv3(AH, AL, wH3 + (u + 0) * 196608, wL3 + (u + 0) * 196608,
                  drb + ((size_t)(i * 4 + j) * 2 + 0) * 256, AH, AL, 0.f, BH, BL, L, d);
            conv3(BH, BL, wH3 + (u + 1) * 196608, wL3 + (u + 1) * 196608,
                  drb + ((size_t)(i * 4 + j) * 2 + 1) * 256, AH, AL, 2.f, AH, AL, L, 1);
        }
        if (i < 4) {
            const ushort_t* wh = w4H + (size_t)(4 + i) * 262144;
            const ushort_t* wl = w4L + (size_t)(4 + i) * 262144;
            if (L >= 8192)
                convt_k<4><<<dim3(L / 64, 1, 2), 256, 0, stream>>>(
                    AH, AL, wh, wl, dub + i * 256, BH, BL, L);
            else if (L >= 4096)
                convt_k<2><<<dim3(L / 32, 1, 2), 256, 0, stream>>>(
                    AH, AL, wh, wl, dub + i * 256, BH, BL, L);
            else
                convt_k<1><<<dim3(L / 16, 1, 2), 256, 0, stream>>>(
                    AH, AL, wh, wl, dub + i * 256, BH, BL, L);
            ushort_t* t;
            t = AH; AH = BH; BH = t;
            t = AL; AL = BL; BL = t;
            L *= 2;
        } else {
            uplast_k2<<<dim3(L / 256, 2), 256, 0, stream>>>(AH, AL, dulw, dulb, out, L);
        }
    }

    commit_write_k<<<1, 1, 0, stream>>>(commit, out + 163840);
}